// Round 5
// baseline (601.232 us; speedup 1.0000x reference)
//
#include <hip/hip_runtime.h>
#include <math.h>

// Problem constants (fixed by the reference):
#define NEXP 4               // n
#define STREAM 4096          // N*C
#define NOUT 24              // n*n + 2n
#define NTOK 16384           // B*L
#define SK_ITERS 20

// Tiling:
#define T_PER_BLOCK 8        // tokens per block (phi reuse factor)
#define CHUNK 512            // k-values staged per chunk
#define NCHUNK (STREAM / CHUNK)   // 8

// ---------------------------------------------------------------------------
// Kernel A: phiT[j][k] = scale[k] * phi[k][j]   (24 x 4096, transposed+scaled)
// ---------------------------------------------------------------------------
__global__ __launch_bounds__(256) void k_transpose_scale(
    const float* __restrict__ phi, const float* __restrict__ scale,
    float* __restrict__ phiT) {
  int flat = blockIdx.x * 256 + threadIdx.x;   // 0..98303, flat = k*24 + j
  int k = flat / NOUT;
  int j = flat - k * NOUT;
  phiT[j * STREAM + k] = phi[flat] * scale[k];
}

// ---------------------------------------------------------------------------
// HBM -> LDS direct DMA, 16 B per lane. No VGPR round-trip; counts in vmcnt
// and is drained by the vmcnt(0) the compiler emits before s_barrier.
// LDS dest is wave-uniform base + lane*16 (m104); our per-lane pointers are
// exactly base + lane*16, so both conventions agree.
// ---------------------------------------------------------------------------
typedef const void __attribute__((address_space(1)))* gas_ptr;
typedef void __attribute__((address_space(3)))* las_ptr;
__device__ __forceinline__ void gl_lds16(const float* g, float* s) {
  __builtin_amdgcn_global_load_lds((gas_ptr)g, (las_ptr)s, 16, 0, 0);
}

// Issue the 4 DMA loads staging chunk `ch` of this wave's two tokens.
__device__ __forceinline__ void stage_issue(
    int ch, int w, int lane, const float* xA, const float* xB, float* buf) {
  const float* gA = xA + ch * CHUNK;
  const float* gB = xB + ch * CHUNK;
  float* dA = buf + (2 * w) * CHUNK;
  float* dB = buf + (2 * w + 1) * CHUNK;
  gl_lds16(gA + 4 * lane,       dA + 4 * lane);
  gl_lds16(gA + 256 + 4 * lane, dA + 256 + 4 * lane);
  gl_lds16(gB + 4 * lane,       dB + 4 * lane);
  gl_lds16(gB + 256 + 4 * lane, dB + 256 + 4 * lane);
}

// Compute on a staged chunk: 6 phi columns (j = 6w+jj) x 8 tokens; ssq for
// this wave's own two tokens re-read from LDS (same values + FP order as the
// verified register-staged path).
__device__ __forceinline__ void compute_chunk(
    int ch, int w, int lane, const float4* __restrict__ phiT4,
    const float* bufC, float (&acc)[T_PER_BLOCK][6],
    float& ssq0, float& ssq1) {
  const float4* l4 = (const float4*)bufC;
  const int pbase = (6 * w) * (STREAM / 4) + ch * (CHUNK / 4);
#pragma unroll
  for (int i = 0; i < 2; i++) {
    int k4 = i * 64 + lane;
    float4 p[6];
#pragma unroll
    for (int jj = 0; jj < 6; jj++)
      p[jj] = phiT4[pbase + jj * (STREAM / 4) + k4];
    {
      float4 va = l4[(2 * w) * (CHUNK / 4) + k4];
      float sa = va.x * va.x + va.y * va.y + va.z * va.z + va.w * va.w;
      ssq0 += sa;
      float4 vb = l4[(2 * w + 1) * (CHUNK / 4) + k4];
      float sb = vb.x * vb.x + vb.y * vb.y + vb.z * vb.z + vb.w * vb.w;
      ssq1 += sb;
    }
#pragma unroll
    for (int t = 0; t < T_PER_BLOCK; t++) {
      float4 xv = l4[t * (CHUNK / 4) + k4];
#pragma unroll
      for (int jj = 0; jj < 6; jj++) {
        float a = acc[t][jj];
        a = fmaf(xv.x, p[jj].x, a);
        a = fmaf(xv.y, p[jj].y, a);
        a = fmaf(xv.z, p[jj].z, a);
        a = fmaf(xv.w, p[jj].w, a);
        acc[t][jj] = a;
      }
    }
  }
}

// ---------------------------------------------------------------------------
// Fused kernel: RMSNorm-dot (matvec) + heads + Sinkhorn, m stays in LDS.
//   Double-buffered x staging via global_load_lds DMA; one barrier per chunk.
//   Schedule: barrier (drains DMA of current chunk) -> issue DMA for next
//   chunk -> compute current. DMA latency hides under ~800 FMA cycles.
// ---------------------------------------------------------------------------
__global__ __launch_bounds__(256, 4) void k_fused(
    const float* __restrict__ x, const float* __restrict__ phiT,
    const float* __restrict__ bias,
    const float* __restrict__ a_pre_p, const float* __restrict__ a_post_p,
    const float* __restrict__ a_res_p, float* __restrict__ out) {
  __shared__ float lds_x0[T_PER_BLOCK * CHUNK];   // 16 KB
  __shared__ float lds_x1[T_PER_BLOCK * CHUNK];   // 16 KB (double buffer)
  __shared__ float lds_m[T_PER_BLOCK * NOUT];     // 192 floats
  __shared__ float lds_inv[T_PER_BLOCK];          // 1/rms per token

  const int tid  = threadIdx.x;
  const int w    = tid >> 6;
  const int lane = tid & 63;
  const int tok0 = blockIdx.x * T_PER_BLOCK;

  const float4* phiT4 = (const float4*)phiT;
  const float* xA = x + (size_t)(tok0 + 2 * w) * STREAM;
  const float* xB = xA + STREAM;

  float acc[T_PER_BLOCK][6];
#pragma unroll
  for (int t = 0; t < T_PER_BLOCK; t++)
#pragma unroll
    for (int jj = 0; jj < 6; jj++) acc[t][jj] = 0.0f;
  float ssq0 = 0.0f, ssq1 = 0.0f;

  // prologue: issue DMA for chunk 0 into buffer 0
  stage_issue(0, w, lane, xA, xB, lds_x0);

  for (int ch = 0; ch < NCHUNK; ch++) {
    float* bufC = (ch & 1) ? lds_x1 : lds_x0;
    float* bufN = (ch & 1) ? lds_x0 : lds_x1;
    __syncthreads();   // vmcnt(0) drain: chunk-ch DMA landed; prev reads done
    if (ch + 1 < NCHUNK)
      stage_issue(ch + 1, w, lane, xA, xB, bufN);   // in flight during compute
    compute_chunk(ch, w, lane, phiT4, bufC, acc, ssq0, ssq1);
  }

  // ---- wave-reduce sumsq (tokens 2w, 2w+1) ----
#pragma unroll
  for (int d = 1; d < 64; d <<= 1) {
    ssq0 += __shfl_xor(ssq0, d, 64);
    ssq1 += __shfl_xor(ssq1, d, 64);
  }
  if (lane == 0) {
    lds_inv[2 * w]     = 1.0f / sqrtf(ssq0 * (1.0f / STREAM) + 1e-20f);
    lds_inv[2 * w + 1] = 1.0f / sqrtf(ssq1 * (1.0f / STREAM) + 1e-20f);
  }

  // ---- wave-reduce the 48 accumulators (butterfly; all lanes get totals) ----
#pragma unroll
  for (int d = 1; d < 64; d <<= 1) {
#pragma unroll
    for (int t = 0; t < T_PER_BLOCK; t++)
#pragma unroll
      for (int jj = 0; jj < 6; jj++)
        acc[t][jj] += __shfl_xor(acc[t][jj], d, 64);
  }
  __syncthreads();   // lds_inv visible to all waves

  // ---- write m into LDS: lane t*6+jj holds token t, column j=6w+jj ----
#pragma unroll
  for (int t = 0; t < T_PER_BLOCK; t++) {
    float inv = lds_inv[t];
#pragma unroll
    for (int jj = 0; jj < 6; jj++) {
      if (lane == t * 6 + jj) {
        int j = 6 * w + jj;
        lds_m[t * NOUT + j] = acc[t][jj] * inv + bias[j];
      }
    }
  }
  __syncthreads();   // lds_m visible

  // ---- heads + Sinkhorn tail: 16 lanes per token, first 2 waves only ----
  if (tid < T_PER_BLOCK * 16) {
    int t = tid >> 4;
    int e = tid & 15;            // r*4 + c
    int tok = tok0 + t;

    const float a_res  = *a_res_p;
    const float a_pre  = *a_pre_p;
    const float a_post = *a_post_p;

    float M = expf(a_res * lds_m[t * NOUT + 2 * NEXP + e]);
#pragma unroll 1
    for (int it = 0; it < SK_ITERS; it++) {
      float rs = M + __shfl_xor(M, 1, 64);
      rs += __shfl_xor(rs, 2, 64);
      M = M / (rs + 1e-12f);
      float cs = M + __shfl_xor(M, 4, 64);
      cs += __shfl_xor(cs, 8, 64);
      M = M / (cs + 1e-12f);
    }
    out[2 * NTOK * NEXP + tok * 16 + e] = M;   // h_res at offset 131072

    if (e < NEXP) {
      float z = a_pre * lds_m[t * NOUT + e];
      out[tok * NEXP + e] = 1.0f / (1.0f + expf(-z));
    } else if (e < 2 * NEXP) {
      int j = e - NEXP;
      float z = a_post * lds_m[t * NOUT + NEXP + j];
      out[NTOK * NEXP + tok * NEXP + j] = 2.0f / (1.0f + expf(-z));
    }
  }
}

// ---------------------------------------------------------------------------
extern "C" void kernel_launch(void* const* d_in, const int* in_sizes, int n_in,
                              void* d_out, int out_size, void* d_ws, size_t ws_size,
                              hipStream_t stream) {
  const float* x      = (const float*)d_in[0];
  const float* scale  = (const float*)d_in[1];
  const float* phi    = (const float*)d_in[2];
  const float* bias   = (const float*)d_in[3];
  const float* a_pre  = (const float*)d_in[4];
  const float* a_post = (const float*)d_in[5];
  const float* a_res  = (const float*)d_in[6];
  float* out = (float*)d_out;

  float* phiT = (float*)d_ws;   // 24*4096 = 98304 floats

  k_transpose_scale<<<(NOUT * STREAM) / 256, 256, 0, stream>>>(phi, scale, phiT);
  k_fused<<<NTOK / T_PER_BLOCK, 256, 0, stream>>>(x, phiT, bias, a_pre, a_post,
                                                  a_res, out);
}

// Round 6
// 413.008 us; speedup vs baseline: 1.4557x; 1.4557x over previous
//
#include <hip/hip_runtime.h>
#include <math.h>

// Problem constants (fixed by the reference):
#define NEXP 4               // n
#define STREAM 4096          // N*C
#define NOUT 24              // n*n + 2n
#define NTOK 16384           // B*L
#define SK_ITERS 20

// Tiling:
#define T_PER_BLOCK 8        // tokens per block (phi reuse factor)
#define CHUNK 512            // k-values staged per chunk
#define NCHUNK (STREAM / CHUNK)   // 8

// ---------------------------------------------------------------------------
// Kernel A: phiT[j][k] = scale[k] * phi[k][j]   (24 x 4096, transposed+scaled)
// ---------------------------------------------------------------------------
__global__ __launch_bounds__(256) void k_transpose_scale(
    const float* __restrict__ phi, const float* __restrict__ scale,
    float* __restrict__ phiT) {
  int flat = blockIdx.x * 256 + threadIdx.x;   // 0..98303, flat = k*24 + j
  int k = flat / NOUT;
  int j = flat - k * NOUT;
  phiT[j * STREAM + k] = phi[flat] * scale[k];
}

// ---------------------------------------------------------------------------
// HBM -> LDS direct DMA, 16 B per lane. No VGPR round-trip; counts in vmcnt
// and is drained by the vmcnt(0) the compiler emits before s_barrier.
// ---------------------------------------------------------------------------
typedef const void __attribute__((address_space(1)))* gas_ptr;
typedef void __attribute__((address_space(3)))* las_ptr;
__device__ __forceinline__ void gl_lds16(const float* g, float* s) {
  __builtin_amdgcn_global_load_lds((gas_ptr)g, (las_ptr)s, 16, 0, 0);
}

// Issue the 4 DMA loads staging chunk `ch` of this wave's two tokens.
__device__ __forceinline__ void stage_issue(
    int ch, int w, int lane, const float* xA, const float* xB, float* buf) {
  const float* gA = xA + ch * CHUNK;
  const float* gB = xB + ch * CHUNK;
  float* dA = buf + (2 * w) * CHUNK;
  float* dB = buf + (2 * w + 1) * CHUNK;
  gl_lds16(gA + 4 * lane,       dA + 4 * lane);
  gl_lds16(gA + 256 + 4 * lane, dA + 256 + 4 * lane);
  gl_lds16(gB + 4 * lane,       dB + 4 * lane);
  gl_lds16(gB + 256 + 4 * lane, dB + 256 + 4 * lane);
}

// Compute on a staged chunk: 6 phi columns (j = 6w+jj) x 8 tokens; ssq for
// this wave's own two tokens re-read from LDS (same values + FP order as the
// verified register-staged path).
__device__ __forceinline__ void compute_chunk(
    int ch, int w, int lane, const float4* __restrict__ phiT4,
    const float* bufC, float (&acc)[T_PER_BLOCK][6],
    float& ssq0, float& ssq1) {
  const float4* l4 = (const float4*)bufC;
  const int pbase = (6 * w) * (STREAM / 4) + ch * (CHUNK / 4);
#pragma unroll
  for (int i = 0; i < 2; i++) {
    int k4 = i * 64 + lane;
    float4 p[6];
#pragma unroll
    for (int jj = 0; jj < 6; jj++)
      p[jj] = phiT4[pbase + jj * (STREAM / 4) + k4];
    {
      float4 va = l4[(2 * w) * (CHUNK / 4) + k4];
      float sa = va.x * va.x + va.y * va.y + va.z * va.z + va.w * va.w;
      ssq0 += sa;
      float4 vb = l4[(2 * w + 1) * (CHUNK / 4) + k4];
      float sb = vb.x * vb.x + vb.y * vb.y + vb.z * vb.z + vb.w * vb.w;
      ssq1 += sb;
    }
#pragma unroll
    for (int t = 0; t < T_PER_BLOCK; t++) {
      float4 xv = l4[t * (CHUNK / 4) + k4];
#pragma unroll
      for (int jj = 0; jj < 6; jj++) {
        float a = acc[t][jj];
        a = fmaf(xv.x, p[jj].x, a);
        a = fmaf(xv.y, p[jj].y, a);
        a = fmaf(xv.z, p[jj].z, a);
        a = fmaf(xv.w, p[jj].w, a);
        acc[t][jj] = a;
      }
    }
  }
}

// ---------------------------------------------------------------------------
// Fused kernel: RMSNorm-dot (matvec) + heads + Sinkhorn, m stays in LDS.
//   Double-buffered x staging via global_load_lds DMA; one barrier per chunk.
//   Schedule: barrier (drains DMA of current chunk) -> issue DMA for next
//   chunk -> compute current. DMA latency hides under ~800 FMA cycles.
//   NOTE: plain __launch_bounds__(256). (256,4) capped VGPR at 64 -> the 48
//   accumulators spilled to scratch (738 MB WRITE_SIZE, R5). Compiler's own
//   allocation (~100 regs, R3: 108) is the right point.
// ---------------------------------------------------------------------------
__global__ __launch_bounds__(256) void k_fused(
    const float* __restrict__ x, const float* __restrict__ phiT,
    const float* __restrict__ bias,
    const float* __restrict__ a_pre_p, const float* __restrict__ a_post_p,
    const float* __restrict__ a_res_p, float* __restrict__ out) {
  __shared__ float lds_x0[T_PER_BLOCK * CHUNK];   // 16 KB
  __shared__ float lds_x1[T_PER_BLOCK * CHUNK];   // 16 KB (double buffer)
  __shared__ float lds_m[T_PER_BLOCK * NOUT];     // 192 floats
  __shared__ float lds_inv[T_PER_BLOCK];          // 1/rms per token

  const int tid  = threadIdx.x;
  const int w    = tid >> 6;
  const int lane = tid & 63;
  const int tok0 = blockIdx.x * T_PER_BLOCK;

  const float4* phiT4 = (const float4*)phiT;
  const float* xA = x + (size_t)(tok0 + 2 * w) * STREAM;
  const float* xB = xA + STREAM;

  float acc[T_PER_BLOCK][6];
#pragma unroll
  for (int t = 0; t < T_PER_BLOCK; t++)
#pragma unroll
    for (int jj = 0; jj < 6; jj++) acc[t][jj] = 0.0f;
  float ssq0 = 0.0f, ssq1 = 0.0f;

  // prologue: issue DMA for chunk 0 into buffer 0
  stage_issue(0, w, lane, xA, xB, lds_x0);

  for (int ch = 0; ch < NCHUNK; ch++) {
    float* bufC = (ch & 1) ? lds_x1 : lds_x0;
    float* bufN = (ch & 1) ? lds_x0 : lds_x1;
    __syncthreads();   // vmcnt(0) drain: chunk-ch DMA landed; prev reads done
    if (ch + 1 < NCHUNK)
      stage_issue(ch + 1, w, lane, xA, xB, bufN);   // in flight during compute
    compute_chunk(ch, w, lane, phiT4, bufC, acc, ssq0, ssq1);
  }

  // ---- wave-reduce sumsq (tokens 2w, 2w+1) ----
#pragma unroll
  for (int d = 1; d < 64; d <<= 1) {
    ssq0 += __shfl_xor(ssq0, d, 64);
    ssq1 += __shfl_xor(ssq1, d, 64);
  }
  if (lane == 0) {
    lds_inv[2 * w]     = 1.0f / sqrtf(ssq0 * (1.0f / STREAM) + 1e-20f);
    lds_inv[2 * w + 1] = 1.0f / sqrtf(ssq1 * (1.0f / STREAM) + 1e-20f);
  }

  // ---- wave-reduce the 48 accumulators (butterfly; all lanes get totals) ----
#pragma unroll
  for (int d = 1; d < 64; d <<= 1) {
#pragma unroll
    for (int t = 0; t < T_PER_BLOCK; t++)
#pragma unroll
      for (int jj = 0; jj < 6; jj++)
        acc[t][jj] += __shfl_xor(acc[t][jj], d, 64);
  }
  __syncthreads();   // lds_inv visible to all waves

  // ---- write m into LDS: lane t*6+jj holds token t, column j=6w+jj ----
#pragma unroll
  for (int t = 0; t < T_PER_BLOCK; t++) {
    float inv = lds_inv[t];
#pragma unroll
    for (int jj = 0; jj < 6; jj++) {
      if (lane == t * 6 + jj) {
        int j = 6 * w + jj;
        lds_m[t * NOUT + j] = acc[t][jj] * inv + bias[j];
      }
    }
  }
  __syncthreads();   // lds_m visible

  // ---- heads + Sinkhorn tail: 16 lanes per token, first 2 waves only ----
  if (tid < T_PER_BLOCK * 16) {
    int t = tid >> 4;
    int e = tid & 15;            // r*4 + c
    int tok = tok0 + t;

    const float a_res  = *a_res_p;
    const float a_pre  = *a_pre_p;
    const float a_post = *a_post_p;

    float M = expf(a_res * lds_m[t * NOUT + 2 * NEXP + e]);
#pragma unroll 1
    for (int it = 0; it < SK_ITERS; it++) {
      float rs = M + __shfl_xor(M, 1, 64);
      rs += __shfl_xor(rs, 2, 64);
      M = M / (rs + 1e-12f);
      float cs = M + __shfl_xor(M, 4, 64);
      cs += __shfl_xor(cs, 8, 64);
      M = M / (cs + 1e-12f);
    }
    out[2 * NTOK * NEXP + tok * 16 + e] = M;   // h_res at offset 131072

    if (e < NEXP) {
      float z = a_pre * lds_m[t * NOUT + e];
      out[tok * NEXP + e] = 1.0f / (1.0f + expf(-z));
    } else if (e < 2 * NEXP) {
      int j = e - NEXP;
      float z = a_post * lds_m[t * NOUT + NEXP + j];
      out[NTOK * NEXP + tok * NEXP + j] = 2.0f / (1.0f + expf(-z));
    }
  }
}

// ---------------------------------------------------------------------------
extern "C" void kernel_launch(void* const* d_in, const int* in_sizes, int n_in,
                              void* d_out, int out_size, void* d_ws, size_t ws_size,
                              hipStream_t stream) {
  const float* x      = (const float*)d_in[0];
  const float* scale  = (const float*)d_in[1];
  const float* phi    = (const float*)d_in[2];
  const float* bias   = (const float*)d_in[3];
  const float* a_pre  = (const float*)d_in[4];
  const float* a_post = (const float*)d_in[5];
  const float* a_res  = (const float*)d_in[6];
  float* out = (float*)d_out;

  float* phiT = (float*)d_ws;   // 24*4096 = 98304 floats

  k_transpose_scale<<<(NOUT * STREAM) / 256, 256, 0, stream>>>(phi, scale, phiT);
  k_fused<<<NTOK / T_PER_BLOCK, 256, 0, stream>>>(x, phiT, bias, a_pre, a_post,
                                                  a_res, out);
}

// Round 7
// 404.934 us; speedup vs baseline: 1.4848x; 1.0199x over previous
//
#include <hip/hip_runtime.h>
#include <math.h>

// Problem constants (fixed by the reference):
#define NEXP 4               // n
#define STREAM 4096          // N*C
#define NOUT 24              // n*n + 2n
#define NTOK 16384           // B*L
#define SK_ITERS 20

// Tiling:
#define T_PER_BLOCK 8        // tokens per block (phi reuse factor)
#define CHUNK 512            // k-values staged per chunk
#define NCHUNK (STREAM / CHUNK)   // 8

// ---------------------------------------------------------------------------
// Kernel A: phiT[j][k] = scale[k] * phi[k][j]   (24 x 4096, transposed+scaled)
// ---------------------------------------------------------------------------
__global__ __launch_bounds__(256) void k_transpose_scale(
    const float* __restrict__ phi, const float* __restrict__ scale,
    float* __restrict__ phiT) {
  int flat = blockIdx.x * 256 + threadIdx.x;   // 0..98303, flat = k*24 + j
  int k = flat / NOUT;
  int j = flat - k * NOUT;
  phiT[j * STREAM + k] = phi[flat] * scale[k];
}

// ---------------------------------------------------------------------------
// HBM -> LDS direct DMA, 16 B per lane. No VGPR round-trip; counts in vmcnt.
// vmcnt retires IN ORDER: any load issued BEFORE these DMAs can be waited on
// without draining them; any load issued AFTER cannot. Hence the strict
// per-chunk issue order below: phiT loads FIRST, DMAs second.
// ---------------------------------------------------------------------------
typedef const void __attribute__((address_space(1)))* gas_ptr;
typedef void __attribute__((address_space(3)))* las_ptr;
__device__ __forceinline__ void gl_lds16(const float* g, float* s) {
  __builtin_amdgcn_global_load_lds((gas_ptr)g, (las_ptr)s, 16, 0, 0);
}

// Issue the 4 DMA loads staging chunk `ch` of this wave's two tokens.
__device__ __forceinline__ void stage_issue(
    int ch, int w, int lane, const float* xA, const float* xB, float* buf) {
  const float* gA = xA + ch * CHUNK;
  const float* gB = xB + ch * CHUNK;
  float* dA = buf + (2 * w) * CHUNK;
  float* dB = buf + (2 * w + 1) * CHUNK;
  gl_lds16(gA + 4 * lane,       dA + 4 * lane);
  gl_lds16(gA + 256 + 4 * lane, dA + 256 + 4 * lane);
  gl_lds16(gB + 4 * lane,       dB + 4 * lane);
  gl_lds16(gB + 256 + 4 * lane, dB + 256 + 4 * lane);
}

// ---------------------------------------------------------------------------
// Fused kernel: RMSNorm-dot (matvec) + heads + Sinkhorn, m stays in LDS.
//   Double-buffered x staging via global_load_lds DMA; one barrier per chunk.
//   Per-chunk schedule (order enforced with sched_barrier(0)):
//     barrier                      // drains DMA(ch) + last chunk's p-loads
//     p0,p1 <- phiT (12 loads)     // issued BEFORE the DMAs -> their waits
//     DMA(ch+1) issue (4)          //   are vmcnt(10)/vmcnt(4), NOT vmcnt(0)
//     compute(ch) on p0/p1 + LDS   // DMAs stay in flight the whole body
// ---------------------------------------------------------------------------
__global__ __launch_bounds__(256) void k_fused(
    const float* __restrict__ x, const float* __restrict__ phiT,
    const float* __restrict__ bias,
    const float* __restrict__ a_pre_p, const float* __restrict__ a_post_p,
    const float* __restrict__ a_res_p, float* __restrict__ out) {
  __shared__ float lds_x0[T_PER_BLOCK * CHUNK];   // 16 KB
  __shared__ float lds_x1[T_PER_BLOCK * CHUNK];   // 16 KB (double buffer)
  __shared__ float lds_m[T_PER_BLOCK * NOUT];     // 192 floats
  __shared__ float lds_inv[T_PER_BLOCK];          // 1/rms per token

  const int tid  = threadIdx.x;
  const int w    = tid >> 6;
  const int lane = tid & 63;
  const int tok0 = blockIdx.x * T_PER_BLOCK;

  const float4* phiT4 = (const float4*)phiT;
  const float* xA = x + (size_t)(tok0 + 2 * w) * STREAM;
  const float* xB = xA + STREAM;

  float acc[T_PER_BLOCK][6];
#pragma unroll
  for (int t = 0; t < T_PER_BLOCK; t++)
#pragma unroll
    for (int jj = 0; jj < 6; jj++) acc[t][jj] = 0.0f;
  float ssq0 = 0.0f, ssq1 = 0.0f;

  // prologue: issue DMA for chunk 0 into buffer 0 (drained by first barrier)
  stage_issue(0, w, lane, xA, xB, lds_x0);

  for (int ch = 0; ch < NCHUNK; ch++) {
    const float* bufC = (ch & 1) ? lds_x1 : lds_x0;
    float*       bufN = (ch & 1) ? lds_x0 : lds_x1;
    __syncthreads();   // vmcnt(0): chunk-ch DMA landed; prev chunk reads done

    // ---- phiT loads FIRST (retire ahead of the DMAs issued below) ----
    const int pbase = (6 * w) * (STREAM / 4) + ch * (CHUNK / 4);
    float4 p0[6], p1[6];
#pragma unroll
    for (int jj = 0; jj < 6; jj++)
      p0[jj] = phiT4[pbase + jj * (STREAM / 4) + lane];
#pragma unroll
    for (int jj = 0; jj < 6; jj++)
      p1[jj] = phiT4[pbase + jj * (STREAM / 4) + 64 + lane];
    __builtin_amdgcn_sched_barrier(0);   // pin: p-loads before DMA issue

    if (ch + 1 < NCHUNK)
      stage_issue(ch + 1, w, lane, xA, xB, bufN);   // in flight during compute
    __builtin_amdgcn_sched_barrier(0);   // pin: DMA issue before compute body

    // ---- compute: 6 phi columns (j = 6w+jj) x 8 tokens; FP order as before --
    const float4* l4 = (const float4*)bufC;
#pragma unroll
    for (int i = 0; i < 2; i++) {
      int k4 = i * 64 + lane;
      {
        float4 va = l4[(2 * w) * (CHUNK / 4) + k4];
        float sa = va.x * va.x + va.y * va.y + va.z * va.z + va.w * va.w;
        ssq0 += sa;
        float4 vb = l4[(2 * w + 1) * (CHUNK / 4) + k4];
        float sb = vb.x * vb.x + vb.y * vb.y + vb.z * vb.z + vb.w * vb.w;
        ssq1 += sb;
      }
#pragma unroll
      for (int t = 0; t < T_PER_BLOCK; t++) {
        float4 xv = l4[t * (CHUNK / 4) + k4];
#pragma unroll
        for (int jj = 0; jj < 6; jj++) {
          float4 p = (i == 0) ? p0[jj] : p1[jj];
          float a = acc[t][jj];
          a = fmaf(xv.x, p.x, a);
          a = fmaf(xv.y, p.y, a);
          a = fmaf(xv.z, p.z, a);
          a = fmaf(xv.w, p.w, a);
          acc[t][jj] = a;
        }
      }
    }
  }

  // ---- wave-reduce sumsq (tokens 2w, 2w+1) ----
#pragma unroll
  for (int d = 1; d < 64; d <<= 1) {
    ssq0 += __shfl_xor(ssq0, d, 64);
    ssq1 += __shfl_xor(ssq1, d, 64);
  }
  if (lane == 0) {
    lds_inv[2 * w]     = 1.0f / sqrtf(ssq0 * (1.0f / STREAM) + 1e-20f);
    lds_inv[2 * w + 1] = 1.0f / sqrtf(ssq1 * (1.0f / STREAM) + 1e-20f);
  }

  // ---- wave-reduce the 48 accumulators (butterfly; all lanes get totals) ----
#pragma unroll
  for (int d = 1; d < 64; d <<= 1) {
#pragma unroll
    for (int t = 0; t < T_PER_BLOCK; t++)
#pragma unroll
      for (int jj = 0; jj < 6; jj++)
        acc[t][jj] += __shfl_xor(acc[t][jj], d, 64);
  }
  __syncthreads();   // lds_inv visible to all waves

  // ---- write m into LDS: lane t*6+jj holds token t, column j=6w+jj ----
#pragma unroll
  for (int t = 0; t < T_PER_BLOCK; t++) {
    float inv = lds_inv[t];
#pragma unroll
    for (int jj = 0; jj < 6; jj++) {
      if (lane == t * 6 + jj) {
        int j = 6 * w + jj;
        lds_m[t * NOUT + j] = acc[t][jj] * inv + bias[j];
      }
    }
  }
  __syncthreads();   // lds_m visible

  // ---- heads + Sinkhorn tail: 16 lanes per token, first 2 waves only ----
  if (tid < T_PER_BLOCK * 16) {
    int t = tid >> 4;
    int e = tid & 15;            // r*4 + c
    int tok = tok0 + t;

    const float a_res  = *a_res_p;
    const float a_pre  = *a_pre_p;
    const float a_post = *a_post_p;

    float M = expf(a_res * lds_m[t * NOUT + 2 * NEXP + e]);
#pragma unroll 1
    for (int it = 0; it < SK_ITERS; it++) {
      float rs = M + __shfl_xor(M, 1, 64);
      rs += __shfl_xor(rs, 2, 64);
      M = M / (rs + 1e-12f);
      float cs = M + __shfl_xor(M, 4, 64);
      cs += __shfl_xor(cs, 8, 64);
      M = M / (cs + 1e-12f);
    }
    out[2 * NTOK * NEXP + tok * 16 + e] = M;   // h_res at offset 131072

    if (e < NEXP) {
      float z = a_pre * lds_m[t * NOUT + e];
      out[tok * NEXP + e] = 1.0f / (1.0f + expf(-z));
    } else if (e < 2 * NEXP) {
      int j = e - NEXP;
      float z = a_post * lds_m[t * NOUT + NEXP + j];
      out[NTOK * NEXP + tok * NEXP + j] = 2.0f / (1.0f + expf(-z));
    }
  }
}

// ---------------------------------------------------------------------------
extern "C" void kernel_launch(void* const* d_in, const int* in_sizes, int n_in,
                              void* d_out, int out_size, void* d_ws, size_t ws_size,
                              hipStream_t stream) {
  const float* x      = (const float*)d_in[0];
  const float* scale  = (const float*)d_in[1];
  const float* phi    = (const float*)d_in[2];
  const float* bias   = (const float*)d_in[3];
  const float* a_pre  = (const float*)d_in[4];
  const float* a_post = (const float*)d_in[5];
  const float* a_res  = (const float*)d_in[6];
  float* out = (float*)d_out;

  float* phiT = (float*)d_ws;   // 24*4096 = 98304 floats

  k_transpose_scale<<<(NOUT * STREAM) / 256, 256, 0, stream>>>(phi, scale, phiT);
  k_fused<<<NTOK / T_PER_BLOCK, 256, 0, stream>>>(x, phiT, bias, a_pre, a_post,
                                                  a_res, out);
}